// Round 4
// baseline (451.831 us; speedup 1.0000x reference)
//
#include <hip/hip_runtime.h>
#include <cstdint>
#include <cstddef>

typedef _Float16 f16;
typedef _Float16 f16x8 __attribute__((ext_vector_type(8)));
typedef _Float16 f16x4 __attribute__((ext_vector_type(4)));
typedef float f32x4 __attribute__((ext_vector_type(4)));

#define AS1 __attribute__((address_space(1)))
#define AS3 __attribute__((address_space(3)))

__device__ __forceinline__ void gl_lds16(const void* g, void* l) {
    __builtin_amdgcn_global_load_lds((const AS1 uint32_t*)g, (AS3 uint32_t*)l, 16, 0, 0);
}

// ---------------------------------------------------------------------------
// Generic f16 GEMM: C[M,N] = A[M,K] @ W[N,K]^T (+bias) (+relu), C stored f16.
// 128x128 tile, BK=32, 4 waves (2x2), each wave 64x64 = 4x4 frags of 16x16.
// M,N multiples of 128; K multiple of 32.
// ---------------------------------------------------------------------------
template<bool BIAS, bool RELU>
__global__ __launch_bounds__(256, 2)
void gemm_kernel(const f16* __restrict__ A, const f16* __restrict__ W,
                 const float* __restrict__ bias, f16* __restrict__ C,
                 int M, int N, int K, int ldw)
{
    __shared__ f16 As[4096];
    __shared__ f16 Bs[4096];
    const int tid  = threadIdx.x;
    const int wave = tid >> 6;
    const int lane = tid & 63;
    const int wm = wave >> 1, wn = wave & 1;
    const int lr = lane & 15, lk = lane >> 4;
    const int row0 = blockIdx.y << 7;
    const int col0 = blockIdx.x << 7;

    // staging: thread tid loads 8 halves: row tid>>2 (0..63), col (tid&3)*8
    const int srow = tid >> 2;
    const int scol = (tid & 3) << 3;
    const f16* Ag = A + (size_t)(row0 + srow) * K + scol;
    const f16* Wg = W + (size_t)(col0 + srow) * ldw + scol;
    f16* lA0 = &As[wave * 512];
    f16* lA1 = &As[2048 + wave * 512];
    f16* lB0 = &Bs[wave * 512];
    f16* lB1 = &Bs[2048 + wave * 512];

    f32x4 acc[4][4] = {};

    for (int k0 = 0; k0 < K; k0 += 32) {
        if (k0) __syncthreads();          // previous tile compute done
        gl_lds16(Ag + k0,                    lA0);
        gl_lds16(Ag + k0 + (size_t)64 * K,   lA1);
        gl_lds16(Wg + k0,                    lB0);
        gl_lds16(Wg + k0 + (size_t)64 * ldw, lB1);
        __syncthreads();                  // drains vmcnt before barrier

        f16x8 af[4], bf[4];
#pragma unroll
        for (int i = 0; i < 4; ++i)
            af[i] = *(const f16x8*)&As[(wm * 64 + i * 16 + lr) * 32 + lk * 8];
#pragma unroll
        for (int i = 0; i < 4; ++i)
            bf[i] = *(const f16x8*)&Bs[(wn * 64 + i * 16 + lr) * 32 + lk * 8];
#pragma unroll
        for (int mi = 0; mi < 4; ++mi)
#pragma unroll
            for (int ni = 0; ni < 4; ++ni)
                acc[mi][ni] = __builtin_amdgcn_mfma_f32_16x16x32_f16(
                    af[mi], bf[ni], acc[mi][ni], 0, 0, 0);
    }

#pragma unroll
    for (int mi = 0; mi < 4; ++mi) {
#pragma unroll
        for (int ni = 0; ni < 4; ++ni) {
#pragma unroll
            for (int j = 0; j < 4; ++j) {
                int r = row0 + wm * 64 + mi * 16 + lk * 4 + j;
                int c = col0 + wn * 64 + ni * 16 + lr;
                float v = acc[mi][ni][j];
                if (BIAS) v += bias[c];
                if (RELU) v = fmaxf(v, 0.0f);
                C[(size_t)r * N + c] = (f16)v;
            }
        }
    }
}

// ---------------------------------------------------------------------------
// Convert fp32 -> f16: slots + 6 weight matrices, one launch. Quad-vectorized.
// ---------------------------------------------------------------------------
__global__ void convert_all_kernel(
    const float* __restrict__ s0, f16* __restrict__ d0,   // slots   2097152
    const float* __restrict__ s1, f16* __restrict__ d1,   // ew1     131072
    const float* __restrict__ s2, f16* __restrict__ d2,   // ew2     262144
    const float* __restrict__ s3, f16* __restrict__ d3,   // ew3     262144
    const float* __restrict__ s4, f16* __restrict__ d4,   // nw1     327680
    const float* __restrict__ s5, f16* __restrict__ d5,   // nw2     262144
    const float* __restrict__ s6, f16* __restrict__ d6)   // nw3      65536
{
    int q = blockIdx.x * 256 + threadIdx.x;   // quad index, total 851968
    const float* s; f16* d; int i;
    if      (q < 524288) { s = s0; d = d0; i = q; }
    else if (q < 557056) { s = s1; d = d1; i = q - 524288; }
    else if (q < 622592) { s = s2; d = d2; i = q - 557056; }
    else if (q < 688128) { s = s3; d = d3; i = q - 622592; }
    else if (q < 770048) { s = s4; d = d4; i = q - 688128; }
    else if (q < 835584) { s = s5; d = d5; i = q - 770048; }
    else                 { s = s6; d = d6; i = q - 835584; }
    const float4 v = *(const float4*)&s[(size_t)i * 4];
    f16x4 o;
    o[0] = (f16)v.x; o[1] = (f16)v.y; o[2] = (f16)v.z; o[3] = (f16)v.w;
    *(f16x4*)&d[(size_t)i * 4] = o;
}

// ---------------------------------------------------------------------------
// e1[row,:] = relu(P[b*8+r,:] + Q[b*8+c,:] + eb1)  (chunk-local rows, H=512)
// ---------------------------------------------------------------------------
__global__ void edge_expand_kernel(const f16* __restrict__ P, const f16* __restrict__ Q,
                                   const float* __restrict__ eb1, f16* __restrict__ E1)
{
    int idx = blockIdx.x * 256 + threadIdx.x;    // nrows*64 total
    int row = idx >> 6;
    int c8  = (idx & 63) << 3;
    int b = row / 56;
    int e = row - b * 56;
    int r = e / 7;
    int t = e - r * 7;
    int cn = t + (t >= r ? 1 : 0);
    f16x8 p = *(const f16x8*)&P[((size_t)(b * 8 + r)  << 9) + c8];
    f16x8 q = *(const f16x8*)&Q[((size_t)(b * 8 + cn) << 9) + c8];
    f16x8 o;
#pragma unroll
    for (int j = 0; j < 8; ++j) {
        float v = (float)p[j] + (float)q[j] + eb1[c8 + j];
        o[j] = (f16)fmaxf(v, 0.0f);
    }
    *(f16x8*)&E1[((size_t)row << 9) + c8] = o;
}

// ---------------------------------------------------------------------------
// In-place relu(layernorm(x)) over last dim (512). One wave per row.
// ---------------------------------------------------------------------------
__global__ void ln_relu_kernel(f16* __restrict__ X, const float* __restrict__ g,
                               const float* __restrict__ b, int rows)
{
    int gw   = (blockIdx.x * 256 + threadIdx.x) >> 6;
    int lane = threadIdx.x & 63;
    if (gw >= rows) return;
    f16* rowp = X + ((size_t)gw << 9);
    f16x8 v = *(const f16x8*)&rowp[lane << 3];
    float f[8];
    float s = 0.f;
#pragma unroll
    for (int j = 0; j < 8; ++j) { f[j] = (float)v[j]; s += f[j]; }
#pragma unroll
    for (int o = 32; o; o >>= 1) s += __shfl_xor(s, o, 64);
    float mean = s * (1.0f / 512.0f);
    float s2 = 0.f;
#pragma unroll
    for (int j = 0; j < 8; ++j) { float d = f[j] - mean; s2 += d * d; }
#pragma unroll
    for (int o = 32; o; o >>= 1) s2 += __shfl_xor(s2, o, 64);
    float rstd = rsqrtf(s2 * (1.0f / 512.0f) + 1e-5f);
    f16x8 ov;
#pragma unroll
    for (int j = 0; j < 8; ++j) {
        int c = (lane << 3) + j;
        float y = (f[j] - mean) * rstd * g[c] + b[c];
        ov[j] = (f16)fmaxf(y, 0.0f);
    }
    *(f16x8*)&rowp[lane << 3] = ov;
}

// ---------------------------------------------------------------------------
// xcat[row,0:128] = slots16c[row,:]; xcat[row,128:640] = sum_{t<7} e3c[...]
// (all pointers chunk-local; row local in [0, nrowsN))
// ---------------------------------------------------------------------------
__global__ void build_xcat_kernel(const f16* __restrict__ slots16, const f16* __restrict__ E3,
                                  f16* __restrict__ xcat)
{
    int idx = blockIdx.x * 256 + threadIdx.x;   // nrowsN*80 total
    int row = idx / 80;
    int ch  = idx - row * 80;
    int b = row >> 3, n = row & 7;
    if (ch < 16) {
        f16x8 v = *(const f16x8*)&slots16[((size_t)row << 7) + (ch << 3)];
        *(f16x8*)&xcat[(size_t)row * 640 + (ch << 3)] = v;
    } else {
        int h8 = (ch - 16) << 3;
        float acc[8] = {};
        const f16* base = E3 + (((size_t)(b * 56 + n * 7)) << 9) + h8;
#pragma unroll
        for (int t = 0; t < 7; ++t) {
            f16x8 v = *(const f16x8*)&base[(size_t)t << 9];
#pragma unroll
            for (int j = 0; j < 8; ++j) acc[j] += (float)v[j];
        }
        f16x8 o;
#pragma unroll
        for (int j = 0; j < 8; ++j) o[j] = (f16)acc[j];
        *(f16x8*)&xcat[(size_t)row * 640 + 128 + h8] = o;
    }
}

// ---------------------------------------------------------------------------
// out[b,:] = (sum_n x3[b,n,:]) @ head_w^T + head_b   (x3 relu'd already)
// ---------------------------------------------------------------------------
__global__ void head_kernel(const f16* __restrict__ x3, const float* __restrict__ hw,
                            const float* __restrict__ hb, float* __restrict__ out)
{
    __shared__ float pooled[128];
    int b = blockIdx.x, t = threadIdx.x;   // 128 threads
    float s = 0.f;
#pragma unroll
    for (int n = 0; n < 8; ++n) s += (float)x3[(((size_t)b * 8 + n) << 7) + t];
    pooled[t] = s;
    __syncthreads();
    if (t < 12) {
        float acc = hb[t];
        for (int d = 0; d < 128; ++d) acc += pooled[d] * hw[t * 128 + d];
        out[b * 12 + t] = acc;
    }
}

// ---------------------------------------------------------------------------
extern "C" void kernel_launch(void* const* d_in, const int* in_sizes, int n_in,
                              void* d_out, int out_size, void* d_ws, size_t ws_size,
                              hipStream_t stream)
{
    const float* slots  = (const float*)d_in[0];
    const float* ew1    = (const float*)d_in[1];
    const float* eb1    = (const float*)d_in[2];
    const float* ew2    = (const float*)d_in[3];
    const float* eb2    = (const float*)d_in[4];
    const float* eln_g  = (const float*)d_in[5];
    const float* eln_b  = (const float*)d_in[6];
    const float* ew3    = (const float*)d_in[7];
    const float* eb3    = (const float*)d_in[8];
    const float* nw1    = (const float*)d_in[9];
    const float* nb1    = (const float*)d_in[10];
    const float* nw2    = (const float*)d_in[11];
    const float* nb2    = (const float*)d_in[12];
    const float* nln_g  = (const float*)d_in[13];
    const float* nln_b  = (const float*)d_in[14];
    const float* nw3    = (const float*)d_in[15];
    const float* nb3    = (const float*)d_in[16];
    const float* head_w = (const float*)d_in[17];
    const float* head_b = (const float*)d_in[18];

    char* ws = (char*)d_ws;
    // Fixed region: slots16 + f16 weights + XCAT  (27,787,264 B)
    f16* slots16 = (f16*)(ws + 0);           //  4,194,304
    f16* w_ew1   = (f16*)(ws + 4194304);     //    262,144
    f16* w_ew2   = (f16*)(ws + 4456448);     //    524,288
    f16* w_ew3   = (f16*)(ws + 4980736);     //    524,288
    f16* w_nw1   = (f16*)(ws + 5505024);     //    655,360
    f16* w_nw2   = (f16*)(ws + 6160384);     //    524,288
    f16* w_nw3   = (f16*)(ws + 6684672);     //    131,072
    f16* XCAT    = (f16*)(ws + 6815744);     // 20,971,520
    char* arena  =        ws + 27787264;     // 131072 * BCH bytes

    // Chunking over batches: arena holds Pc,Qc,E1c,E2c for BCH batches.
    // total ws need = 27,787,264 + 131072*BCH  (requires BCH>=256 -> 58.5 MB)
    const size_t FIXED = 27787264ULL;
    int BCH;
    if      (ws_size >= FIXED + 131072ULL * 2048) BCH = 2048;  // 282.6 MB: unchunked
    else if (ws_size >= FIXED + 131072ULL * 512)  BCH = 512;   //  90.5 MB: 4 chunks
    else                                          BCH = 256;   //  58.5 MB: 8 chunks
    const int nch = 2048 / BCH;
    const int RN  = BCH * 8;    // node rows per chunk   (mult of 128)
    const int RE  = BCH * 56;   // edge rows per chunk   (mult of 128)

    f16* Pc  = (f16*)(arena);
    f16* Qc  = (f16*)(arena + (size_t)8192 * BCH);
    f16* E1c = (f16*)(arena + (size_t)16384 * BCH);
    f16* E2c = (f16*)(arena + (size_t)16384 * BCH + (size_t)57344 * BCH);

    // Node-MLP buffers (used after all chunks; arena & slots16 dead by then)
    f16* X1 = (f16*)(arena);                  // 16,777,216
    f16* X2 = (f16*)(arena + 16777216);       // 16,777,216  (arena >= 33.5MB for BCH>=256)
    f16* X3 = (f16*)(ws);                     //  4,194,304  (over slots16, exact)
    float* out = (float*)d_out;

    convert_all_kernel<<<dim3(3328), 256, 0, stream>>>(
        slots, slots16, ew1, w_ew1, ew2, w_ew2, ew3, w_ew3,
        nw1, w_nw1, nw2, w_nw2, nw3, w_nw3);

    for (int c = 0; c < nch; ++c) {
        const f16* sc = slots16 + (size_t)c * RN * 128;
        // Pc = slots_c @ ew1[:, :128]^T ; Qc = slots_c @ ew1[:, 128:]^T
        gemm_kernel<false,false><<<dim3(4, RN/128), 256, 0, stream>>>(sc, w_ew1,       nullptr, Pc, RN, 512, 128, 256);
        gemm_kernel<false,false><<<dim3(4, RN/128), 256, 0, stream>>>(sc, w_ew1 + 128, nullptr, Qc, RN, 512, 128, 256);
        // e1 = relu(P[row]+Q[col]+eb1)
        edge_expand_kernel<<<dim3(RE/4), 256, 0, stream>>>(Pc, Qc, eb1, E1c);
        // e2 = e1 @ ew2^T + eb2 ; relu(LN) in place
        gemm_kernel<true,false><<<dim3(4, RE/128), 256, 0, stream>>>(E1c, w_ew2, eb2, E2c, RE, 512, 512, 512);
        ln_relu_kernel<<<dim3(RE/4), 256, 0, stream>>>(E2c, eln_g, eln_b, RE);
        // e3 = e2ln @ ew3^T + eb3   (overwrites E1c)
        gemm_kernel<true,false><<<dim3(4, RE/128), 256, 0, stream>>>(E2c, w_ew3, eb3, E1c, RE, 512, 512, 512);
        // xcat chunk
        build_xcat_kernel<<<dim3(RN*5/16), 256, 0, stream>>>(sc, E1c, XCAT + (size_t)c * RN * 640);
    }

    // node MLP (full 16384 rows)
    gemm_kernel<true,true ><<<dim3(4,128), 256, 0, stream>>>(XCAT, w_nw1, nb1, X1, 16384, 512, 640, 640);
    gemm_kernel<true,false><<<dim3(4,128), 256, 0, stream>>>(X1,   w_nw2, nb2, X2, 16384, 512, 512, 512);
    ln_relu_kernel<<<dim3(4096), 256, 0, stream>>>(X2, nln_g, nln_b, 16384);
    gemm_kernel<true,true ><<<dim3(1,128), 256, 0, stream>>>(X2,   w_nw3, nb3, X3, 16384, 128, 512, 512);

    head_kernel<<<dim3(2048), 128, 0, stream>>>(X3, head_w, head_b, out);
}

// Round 5
// 272.614 us; speedup vs baseline: 1.6574x; 1.6574x over previous
//
#include <hip/hip_runtime.h>
#include <cstdint>
#include <cstddef>

typedef _Float16 f16;
typedef _Float16 f16x8 __attribute__((ext_vector_type(8)));
typedef _Float16 f16x4 __attribute__((ext_vector_type(4)));
typedef float f32x4 __attribute__((ext_vector_type(4)));

#define AS1 __attribute__((address_space(1)))
#define AS3 __attribute__((address_space(3)))

__device__ __forceinline__ void gl_lds16(const void* g, void* l) {
    __builtin_amdgcn_global_load_lds((const AS1 uint32_t*)g, (AS3 uint32_t*)l, 16, 0, 0);
}

// ---------------------------------------------------------------------------
// Generic f16 GEMM: C[M,N] = A[M,K]@W[N,K]^T (+bias*bscale)(+relu), C f16.
// 128x128 tile, BK=32, 4 waves. M,N mult of 128; K mult of 32.
// ---------------------------------------------------------------------------
template<bool BIAS, bool RELU>
__global__ __launch_bounds__(256, 2)
void gemm_kernel(const f16* __restrict__ A, int lda,
                 const f16* __restrict__ W, int ldw,
                 const float* __restrict__ bias, float bscale,
                 f16* __restrict__ C, int ldc, int K)
{
    __shared__ f16 As[4096];
    __shared__ f16 Bs[4096];
    const int tid  = threadIdx.x;
    const int wave = tid >> 6;
    const int lane = tid & 63;
    const int wm = wave >> 1, wn = wave & 1;
    const int lr = lane & 15, lk = lane >> 4;
    const int row0 = blockIdx.y << 7;
    const int col0 = blockIdx.x << 7;

    const int srow = tid >> 2;
    const int scol = (tid & 3) << 3;
    const f16* Ag = A + (size_t)(row0 + srow) * lda + scol;
    const f16* Wg = W + (size_t)(col0 + srow) * ldw + scol;
    f16* lA0 = &As[wave * 512];
    f16* lA1 = &As[2048 + wave * 512];
    f16* lB0 = &Bs[wave * 512];
    f16* lB1 = &Bs[2048 + wave * 512];

    f32x4 acc[4][4] = {};

    for (int k0 = 0; k0 < K; k0 += 32) {
        if (k0) __syncthreads();
        gl_lds16(Ag + k0,                    lA0);
        gl_lds16(Ag + k0 + (size_t)64 * lda, lA1);
        gl_lds16(Wg + k0,                    lB0);
        gl_lds16(Wg + k0 + (size_t)64 * ldw, lB1);
        __syncthreads();

        f16x8 af[4], bf[4];
#pragma unroll
        for (int i = 0; i < 4; ++i)
            af[i] = *(const f16x8*)&As[(wm * 64 + i * 16 + lr) * 32 + lk * 8];
#pragma unroll
        for (int i = 0; i < 4; ++i)
            bf[i] = *(const f16x8*)&Bs[(wn * 64 + i * 16 + lr) * 32 + lk * 8];
#pragma unroll
        for (int mi = 0; mi < 4; ++mi)
#pragma unroll
            for (int ni = 0; ni < 4; ++ni)
                acc[mi][ni] = __builtin_amdgcn_mfma_f32_16x16x32_f16(
                    af[mi], bf[ni], acc[mi][ni], 0, 0, 0);
    }

#pragma unroll
    for (int mi = 0; mi < 4; ++mi) {
#pragma unroll
        for (int ni = 0; ni < 4; ++ni) {
#pragma unroll
            for (int j = 0; j < 4; ++j) {
                int r = row0 + wm * 64 + mi * 16 + lk * 4 + j;
                int c = col0 + wn * 64 + ni * 16 + lr;
                float v = acc[mi][ni][j];
                if (BIAS) v += bias[c] * bscale;
                if (RELU) v = fmaxf(v, 0.0f);
                C[(size_t)r * ldc + c] = (f16)v;
            }
        }
    }
}

// ---------------------------------------------------------------------------
// Fused GEMM + (bias) + LayerNorm + relu. Tile BM x 512, K=512, 8 waves.
// EDGE: A built on-the-fly = relu(P[src]+Q[tgt]+eb1) from P,Q (chunk-local).
// PLAIN: A from global, lda given. Output f16, ldc given.
// BM=128 (edge): waves 2x4 (wave 64x128). BM=64 (node): waves 1x8 (64x64).
// ---------------------------------------------------------------------------
template<int BM, bool EDGE>
__global__ __launch_bounds__(512, 2)
void fused_gemm_ln(const f16* __restrict__ A, const f16* __restrict__ Q,
                   const f16* __restrict__ EB1, int lda,
                   const f16* __restrict__ W,
                   const float* __restrict__ bias,
                   const float* __restrict__ g, const float* __restrict__ b,
                   f16* __restrict__ C, int ldc)
{
    constexpr int NI  = (BM == 128) ? 8 : 4;   // 16-col frags per wave
    constexpr int NWN = 512 / (NI * 16);       // waves across N: 4 or 8
    __shared__ f16 As[BM * 32];
    __shared__ f16 Bs[512 * 32];
    __shared__ float lnred[BM * NWN * 2];
    __shared__ float stat[BM * 2];

    const int tid  = threadIdx.x;
    const int wave = tid >> 6;
    const int lane = tid & 63;
    const int wm = (BM == 128) ? (wave >> 2) : 0;
    const int wn = (BM == 128) ? (wave & 3) : wave;
    const int lr = lane & 15, lk = lane >> 4;
    const int row0 = blockIdx.x * BM;
    const int wcol0 = wn * (NI * 16);

    // ---- A-source precompute ----
    const f16 *Pr = nullptr, *Qr = nullptr;
    const f16 *Ar = nullptr;
    if (EDGE) {
        int erow = row0 + (tid >> 2);
        int bb = erow / 56;
        int e  = erow - bb * 56;
        int r  = e / 7;
        int t2 = e - r * 7;
        int cn = t2 + (t2 >= r ? 1 : 0);
        Pr = A + ((size_t)(bb * 8 + r)  << 9) + ((tid & 3) << 3);
        Qr = Q + ((size_t)(bb * 8 + cn) << 9) + ((tid & 3) << 3);
    } else {
        Ar = A + (size_t)(row0 + (tid >> 2)) * lda + ((tid & 3) << 3);
    }

    f32x4 acc[4][NI] = {};

    for (int k0 = 0; k0 < 512; k0 += 32) {
        if (k0) __syncthreads();
        // stage B: 512 rows x 32 halves via global_load_lds (4 chunks/thread)
#pragma unroll
        for (int i = 0; i < 4; ++i) {
            int chunk = i * 512 + tid;
            gl_lds16(W + (size_t)(chunk >> 2) * 512 + k0 + ((chunk & 3) << 3),
                     &Bs[(i * 512 + wave * 64) * 8]);
        }
        // stage A
        if (EDGE) {
            f16x8 p  = *(const f16x8*)(Pr + k0);
            f16x8 q  = *(const f16x8*)(Qr + k0);
            f16x8 eb = *(const f16x8*)&EB1[k0 + ((tid & 3) << 3)];
            f16x8 o;
#pragma unroll
            for (int j = 0; j < 8; ++j)
                o[j] = (f16)fmaxf((float)p[j] + (float)q[j] + (float)eb[j], 0.0f);
            *(f16x8*)&As[(tid >> 2) * 32 + ((tid & 3) << 3)] = o;
        } else {
            if (wave < BM / 32)   // BM=64: waves 0,1 (128 threads*... ) -> see note
                ;
            // PLAIN: stage BM x 32 halves: BM*4 chunks; use first BM*4 threads
            if (tid < BM * 4)
                gl_lds16(Ar + k0, &As[wave * 512]);
        }
        __syncthreads();

        f16x8 af[4], bf[NI];
#pragma unroll
        for (int i = 0; i < 4; ++i)
            af[i] = *(const f16x8*)&As[(wm * 64 + i * 16 + lr) * 32 + lk * 8];
#pragma unroll
        for (int i = 0; i < NI; ++i)
            bf[i] = *(const f16x8*)&Bs[(wcol0 + i * 16 + lr) * 32 + lk * 8];
#pragma unroll
        for (int mi = 0; mi < 4; ++mi)
#pragma unroll
            for (int ni = 0; ni < NI; ++ni)
                acc[mi][ni] = __builtin_amdgcn_mfma_f32_16x16x32_f16(
                    af[mi], bf[ni], acc[mi][ni], 0, 0, 0);
    }

    // ---- epilogue: bias, LN stats, normalize, relu, store ----
    float biasv[NI], gv[NI], bv[NI];
#pragma unroll
    for (int ni = 0; ni < NI; ++ni) {
        int col = wcol0 + ni * 16 + lr;
        biasv[ni] = bias[col];
        gv[ni] = g[col];
        bv[ni] = b[col];
    }
#pragma unroll
    for (int mi = 0; mi < 4; ++mi)
#pragma unroll
        for (int ni = 0; ni < NI; ++ni)
#pragma unroll
            for (int j = 0; j < 4; ++j)
                acc[mi][ni][j] += biasv[ni];

#pragma unroll
    for (int mi = 0; mi < 4; ++mi) {
#pragma unroll
        for (int j = 0; j < 4; ++j) {
            float s = 0.f, s2 = 0.f;
#pragma unroll
            for (int ni = 0; ni < NI; ++ni) {
                float v = acc[mi][ni][j];
                s += v; s2 += v * v;
            }
#pragma unroll
            for (int o = 1; o < 16; o <<= 1) {
                s  += __shfl_xor(s,  o, 64);
                s2 += __shfl_xor(s2, o, 64);
            }
            if (lr == 0) {
                int row = wm * 64 + mi * 16 + lk * 4 + j;
                lnred[(row * NWN + wn) * 2 + 0] = s;
                lnred[(row * NWN + wn) * 2 + 1] = s2;
            }
        }
    }
    __syncthreads();
    if (tid < BM) {
        float s = 0.f, s2 = 0.f;
#pragma unroll
        for (int w = 0; w < NWN; ++w) {
            s  += lnred[(tid * NWN + w) * 2 + 0];
            s2 += lnred[(tid * NWN + w) * 2 + 1];
        }
        float mean = s * (1.0f / 512.0f);
        float var  = fmaxf(s2 * (1.0f / 512.0f) - mean * mean, 0.0f);
        stat[tid * 2 + 0] = mean;
        stat[tid * 2 + 1] = rsqrtf(var + 1e-5f);
    }
    __syncthreads();

#pragma unroll
    for (int mi = 0; mi < 4; ++mi) {
#pragma unroll
        for (int j = 0; j < 4; ++j) {
            int row = wm * 64 + mi * 16 + lk * 4 + j;
            float mean = stat[row * 2 + 0];
            float rstd = stat[row * 2 + 1];
            size_t gr = (size_t)(row0 + row) * ldc;
#pragma unroll
            for (int ni = 0; ni < NI; ++ni) {
                float y = (acc[mi][ni][j] - mean) * rstd * gv[ni] + bv[ni];
                C[gr + wcol0 + ni * 16 + lr] = (f16)fmaxf(y, 0.0f);
            }
        }
    }
}

// ---------------------------------------------------------------------------
// Convert fp32 -> f16. Slots go strided into XCAT cols 0:128 (ldc=640).
// ---------------------------------------------------------------------------
__global__ void convert_all_kernel(
    const float* __restrict__ s0, f16* __restrict__ xcat,  // slots -> strided
    const float* __restrict__ s1, f16* __restrict__ d1,    // ew1   32768 q
    const float* __restrict__ s2, f16* __restrict__ d2,    // ew2   65536 q
    const float* __restrict__ s3, f16* __restrict__ d3,    // ew3   65536 q
    const float* __restrict__ s4, f16* __restrict__ d4,    // nw1   81920 q
    const float* __restrict__ s5, f16* __restrict__ d5,    // nw2   65536 q
    const float* __restrict__ s6, f16* __restrict__ d6,    // nw3   16384 q
    const float* __restrict__ s7, f16* __restrict__ d7)    // eb1     128 q
{
    int q = blockIdx.x * 256 + threadIdx.x;
    if (q >= 852096) return;
    if (q < 524288) {                       // slots: row=q>>5, col=(q&31)*4
        const float4 v = *(const float4*)&s0[(size_t)q * 4];
        f16x4 o; o[0]=(f16)v.x; o[1]=(f16)v.y; o[2]=(f16)v.z; o[3]=(f16)v.w;
        int row = q >> 5, col = (q & 31) << 2;
        *(f16x4*)&xcat[(size_t)row * 640 + col] = o;
        return;
    }
    const float* s; f16* d; int i;
    if      (q < 557056) { s = s1; d = d1; i = q - 524288; }
    else if (q < 622592) { s = s2; d = d2; i = q - 557056; }
    else if (q < 688128) { s = s3; d = d3; i = q - 622592; }
    else if (q < 770048) { s = s4; d = d4; i = q - 688128; }
    else if (q < 835584) { s = s5; d = d5; i = q - 770048; }
    else if (q < 851968) { s = s6; d = d6; i = q - 835584; }
    else                 { s = s7; d = d7; i = q - 851968; }
    const float4 v = *(const float4*)&s[(size_t)i * 4];
    f16x4 o; o[0]=(f16)v.x; o[1]=(f16)v.y; o[2]=(f16)v.z; o[3]=(f16)v.w;
    *(f16x4*)&d[(size_t)i * 4] = o;
}

// ---------------------------------------------------------------------------
// AGG[row,:] = sum_{t<7} E2LN[b*56+n*7+t, :]   (row=b*8+n chunk-local)
// ---------------------------------------------------------------------------
__global__ void agg_kernel(const f16* __restrict__ E2, f16* __restrict__ AGG)
{
    int idx = blockIdx.x * 256 + threadIdx.x;   // RN*64 total
    int row = idx >> 6;
    int c8  = (idx & 63) << 3;
    int bb = row >> 3, n = row & 7;
    const f16* base = E2 + (((size_t)(bb * 56 + n * 7)) << 9) + c8;
    float acc[8] = {};
#pragma unroll
    for (int t = 0; t < 7; ++t) {
        f16x8 v = *(const f16x8*)&base[(size_t)t << 9];
#pragma unroll
        for (int j = 0; j < 8; ++j) acc[j] += (float)v[j];
    }
    f16x8 o;
#pragma unroll
    for (int j = 0; j < 8; ++j) o[j] = (f16)acc[j];
    *(f16x8*)&AGG[((size_t)row << 9) + c8] = o;
}

// ---------------------------------------------------------------------------
// out[b,:] = (sum_n x3[b,n,:]) @ head_w^T + head_b
// ---------------------------------------------------------------------------
__global__ void head_kernel(const f16* __restrict__ x3, const float* __restrict__ hw,
                            const float* __restrict__ hb, float* __restrict__ out)
{
    __shared__ float pooled[128];
    int b = blockIdx.x, t = threadIdx.x;   // 128 threads
    float s = 0.f;
#pragma unroll
    for (int n = 0; n < 8; ++n) s += (float)x3[(((size_t)b * 8 + n) << 7) + t];
    pooled[t] = s;
    __syncthreads();
    if (t < 12) {
        float acc = hb[t];
        for (int d = 0; d < 128; ++d) acc += pooled[d] * hw[t * 128 + d];
        out[b * 12 + t] = acc;
    }
}

// ---------------------------------------------------------------------------
extern "C" void kernel_launch(void* const* d_in, const int* in_sizes, int n_in,
                              void* d_out, int out_size, void* d_ws, size_t ws_size,
                              hipStream_t stream)
{
    const float* slots  = (const float*)d_in[0];
    const float* ew1    = (const float*)d_in[1];
    const float* eb1    = (const float*)d_in[2];
    const float* ew2    = (const float*)d_in[3];
    const float* eb2    = (const float*)d_in[4];
    const float* eln_g  = (const float*)d_in[5];
    const float* eln_b  = (const float*)d_in[6];
    const float* ew3    = (const float*)d_in[7];
    const float* eb3    = (const float*)d_in[8];
    const float* nw1    = (const float*)d_in[9];
    const float* nb1    = (const float*)d_in[10];
    const float* nw2    = (const float*)d_in[11];
    const float* nb2    = (const float*)d_in[12];
    const float* nln_g  = (const float*)d_in[13];
    const float* nln_b  = (const float*)d_in[14];
    const float* nw3    = (const float*)d_in[15];
    const float* nb3    = (const float*)d_in[16];
    const float* head_w = (const float*)d_in[17];
    const float* head_b = (const float*)d_in[18];

    char* ws = (char*)d_ws;
    f16* XCAT   = (f16*)(ws + 0);            // 16384*640*2 = 20,971,520
    f16* w_ew1  = (f16*)(ws + 20971520);     //   262,144
    f16* w_ew2  = (f16*)(ws + 21233664);     //   524,288
    f16* w_ew3  = (f16*)(ws + 21757952);     //   524,288
    f16* w_nw1  = (f16*)(ws + 22282240);     //   655,360
    f16* w_nw2  = (f16*)(ws + 22937600);     //   524,288
    f16* w_nw3  = (f16*)(ws + 23461888);     //   131,072
    f16* eb1_16 = (f16*)(ws + 23592960);     //     1,024
    f16* AGG    = (f16*)(ws + 23593984);     // 16,777,216
    char* arena =        ws + 40371200;      // 73728*BCH

    const size_t FIXED = 40371200ULL;
    int BCH;
    if      (ws_size >= FIXED + 73728ULL * 2048) BCH = 2048;  // 191.4 MB
    else if (ws_size >= FIXED + 73728ULL * 512)  BCH = 512;   //  78.1 MB
    else                                         BCH = 256;   //  59.2 MB
    const int nch = 2048 / BCH;
    const int RN  = BCH * 8;    // node rows / chunk (mult 128)
    const int RE  = BCH * 56;   // edge rows / chunk (mult 128)

    f16* Pc  = (f16*)(arena);
    f16* Qc  = (f16*)(arena + (size_t)8192  * BCH);
    f16* E2c = (f16*)(arena + (size_t)16384 * BCH);   // 57344*BCH bytes

    f16* X1 = AGG;            // 16 MB, after AGG consumed
    f16* X2 = (f16*)(arena);  // 16 MB
    f16* X3 = XCAT;           //  4 MB, after XCAT consumed
    float* out = (float*)d_out;

    convert_all_kernel<<<dim3(3329), 256, 0, stream>>>(
        slots, XCAT, ew1, w_ew1, ew2, w_ew2, ew3, w_ew3,
        nw1, w_nw1, nw2, w_nw2, nw3, w_nw3, eb1, eb1_16);

    for (int c = 0; c < nch; ++c) {
        const f16* sc = XCAT + (size_t)c * RN * 640;
        // P = slots@ew1[:,:128]^T ; Q = slots@ew1[:,128:]^T
        gemm_kernel<false,false><<<dim3(4, RN/128), 256, 0, stream>>>(
            sc, 640, w_ew1,       256, nullptr, 1.0f, Pc, 512, 128);
        gemm_kernel<false,false><<<dim3(4, RN/128), 256, 0, stream>>>(
            sc, 640, w_ew1 + 128, 256, nullptr, 1.0f, Qc, 512, 128);
        // e2ln = relu(LN(relu(P+Q+eb1) @ ew2^T + eb2))
        fused_gemm_ln<128,true><<<dim3(RE/128), 512, 0, stream>>>(
            Pc, Qc, eb1_16, 0, w_ew2, eb2, eln_g, eln_b, E2c, 512);
        // agg = segment-sum over 7 edges per node
        agg_kernel<<<dim3(RN/4), 256, 0, stream>>>(E2c, AGG + (size_t)c * RN * 512);
    }

    // xcat[:,128:640] = AGG @ ew3^T + 7*eb3   (linearity of segment-sum)
    gemm_kernel<true,false><<<dim3(4,128), 256, 0, stream>>>(
        AGG, 512, w_ew3, 512, eb3, 7.0f, XCAT + 128, 640, 512);
    // x1 = relu(xcat @ nw1^T + nb1)
    gemm_kernel<true,true ><<<dim3(4,128), 256, 0, stream>>>(
        XCAT, 640, w_nw1, 640, nb1, 1.0f, X1, 512, 640);
    // x2 = relu(LN(x1 @ nw2^T + nb2))
    fused_gemm_ln<64,false><<<dim3(256), 512, 0, stream>>>(
        X1, nullptr, nullptr, 512, w_nw2, nb2, nln_g, nln_b, X2, 512);
    // x3 = relu(x2 @ nw3^T + nb3)
    gemm_kernel<true,true ><<<dim3(1,128), 256, 0, stream>>>(
        X2, 512, w_nw3, 512, nb3, 1.0f, X3, 128, 512);

    head_kernel<<<dim3(2048), 128, 0, stream>>>(X3, head_w, head_b, out);
}